// Round 1
// baseline (353.969 us; speedup 1.0000x reference)
//
#include <hip/hip_runtime.h>
#include <hip/hip_bf16.h>
#include <stdint.h>

typedef __attribute__((ext_vector_type(8))) __bf16 bf16x8;
typedef __attribute__((ext_vector_type(4))) float floatx4;

// ---------------------------------------------------------------------------
// f32 -> bf16 round-to-nearest-even (values here are exactly representable,
// so this is exact; RNE kept for safety)
__device__ __forceinline__ uint16_t f32_to_bf16_rn(float f) {
    uint32_t u = __float_as_uint(f);
    uint32_t r = u + 0x7FFFu + ((u >> 16) & 1u);
    return (uint16_t)(r >> 16);
}

// ---------------------------------------------------------------------------
// MX quant (block=32 along K, e8m0 shared scale, e4m3 element grid, rint)
// then immediate dequant, stored as bf16 (exact).
// One lane handles 4 consecutive floats; a group of 8 lanes = one MX block.
__global__ __launch_bounds__(256) void quant_dq_kernel(
    const float* __restrict__ in, uint16_t* __restrict__ out, int n4)
{
    int t = blockIdx.x * blockDim.x + threadIdx.x;
    if (t >= n4) return;
    float4 v = ((const float4*)in)[t];

    float am = fmaxf(fmaxf(fabsf(v.x), fabsf(v.y)), fmaxf(fabsf(v.z), fabsf(v.w)));
    am = fmaxf(am, __shfl_xor(am, 1));
    am = fmaxf(am, __shfl_xor(am, 2));
    am = fmaxf(am, __shfl_xor(am, 4));

    float scale, iscale;
    if (am > 0.0f) {
        // floor(log2(am)) == unbiased exponent (subnormal -> -127, clamps same as ref)
        int se = (int)((__float_as_uint(am) >> 23) & 0xFF) - 127 - 8;
        se = se < -127 ? -127 : se;
        scale  = __uint_as_float((uint32_t)(se + 127) << 23);
        iscale = __uint_as_float((uint32_t)(127 - se) << 23);
    } else {
        scale = 1.0f; iscale = 1.0f;
    }

    float r[4] = {v.x, v.y, v.z, v.w};
    uint16_t o[4];
#pragma unroll
    for (int i = 0; i < 4; ++i) {
        float sv = r[i] * iscale;              // exact (power-of-two)
        float a  = fabsf(sv);
        int e = (int)((__float_as_uint(a) >> 23) & 0xFF) - 127;
        e = e < -6 ? -6 : (e > 8 ? 8 : e);
        float step  = __uint_as_float((uint32_t)(e - 3 + 127) << 23);
        float rstep = __uint_as_float((uint32_t)(3 - e + 127) << 23);
        float q = rintf(a * rstep) * step;     // exact grid snap, RNE like jnp.round
        q = fminf(q, 448.0f);
        float dq = copysignf(q, sv) * scale;   // exact in bf16
        o[i] = f32_to_bf16_rn(dq);
    }
    ((ushort4*)out)[t] = make_ushort4(o[0], o[1], o[2], o[3]);
}

// ---------------------------------------------------------------------------
// bf16 GEMM, C[M,N] = A[M,K] * B[N,K]^T + bias[N]
// 128x128 block tile, BK=64, 256 threads (4 waves, 2x2 wave grid, each wave
// 4x4 tiles of 16x16x32 MFMA). global_load_lds width=16 staging (m97 style).
#define BM 128
#define BN 128
#define BK 64

__global__ __launch_bounds__(256) void gemm_bt_bias(
    const uint16_t* __restrict__ A, const uint16_t* __restrict__ B,
    const float* __restrict__ bias, float* __restrict__ C,
    int M, int N, int K)
{
    __shared__ uint16_t sA[BM * BK];   // [row][k], 128 B per row, no padding
    __shared__ uint16_t sB[BN * BK];

    const int tid  = threadIdx.x;
    const int wave = tid >> 6;
    const int lane = tid & 63;

    const int bm = blockIdx.y * BM;
    const int bn = blockIdx.x * BN;

    // staging: wave w loads rows [w*32, w*32+32), 4 calls x 8 rows x 128 B.
    // lane l -> row +l/8, 16B chunk (l%8) within the row (matches HW's
    // wave-uniform-base + lane*16 LDS scatter).
    const int strow = wave * 32 + (lane >> 3);
    const int stcol = (lane & 7) * 8;

    const uint16_t* Ag = A + (size_t)(bm + strow) * K + stcol;
    const uint16_t* Bg = B + (size_t)(bn + strow) * K + stcol;

    const int wm = (wave & 1) * 64;
    const int wn = (wave >> 1) * 64;
    const int fr = lane & 15;   // m (A) / n (B) index within 16-tile
    const int fq = lane >> 4;   // quad -> k offset fq*8

    floatx4 zero = {0.0f, 0.0f, 0.0f, 0.0f};
    floatx4 acc[4][4];
#pragma unroll
    for (int i = 0; i < 4; ++i)
#pragma unroll
        for (int j = 0; j < 4; ++j) acc[i][j] = zero;

    for (int k0 = 0; k0 < K; k0 += BK) {
        __syncthreads();   // protect LDS from overwrite while prior tile in use
#pragma unroll
        for (int c = 0; c < 4; ++c) {
            __builtin_amdgcn_global_load_lds(
                (const __attribute__((address_space(1))) void*)(Ag + (size_t)c * 8 * K + k0),
                (__attribute__((address_space(3))) void*)(sA + (wave * 32 + c * 8) * BK),
                16, 0, 0);
        }
#pragma unroll
        for (int c = 0; c < 4; ++c) {
            __builtin_amdgcn_global_load_lds(
                (const __attribute__((address_space(1))) void*)(Bg + (size_t)c * 8 * K + k0),
                (__attribute__((address_space(3))) void*)(sB + (wave * 32 + c * 8) * BK),
                16, 0, 0);
        }
        __syncthreads();   // drains vmcnt before LDS reads

#pragma unroll
        for (int kk = 0; kk < BK; kk += 32) {
            bf16x8 af[4], bf[4];
#pragma unroll
            for (int u = 0; u < 4; ++u)
                af[u] = *(const bf16x8*)(sA + (wm + u * 16 + fr) * BK + kk + fq * 8);
#pragma unroll
            for (int u = 0; u < 4; ++u)
                bf[u] = *(const bf16x8*)(sB + (wn + u * 16 + fr) * BK + kk + fq * 8);
#pragma unroll
            for (int i = 0; i < 4; ++i)
#pragma unroll
                for (int j = 0; j < 4; ++j)
                    acc[i][j] = __builtin_amdgcn_mfma_f32_16x16x32_bf16(
                        af[i], bf[j], acc[i][j], 0, 0, 0);
        }
    }

    // epilogue: C/D layout col = lane&15, row = (lane>>4)*4 + reg
    float bz[4];
#pragma unroll
    for (int j = 0; j < 4; ++j) bz[j] = bias[bn + wn + j * 16 + fr];

#pragma unroll
    for (int i = 0; i < 4; ++i) {
        int row0 = bm + wm + i * 16 + fq * 4;
#pragma unroll
        for (int j = 0; j < 4; ++j) {
            int col = bn + wn + j * 16 + fr;
#pragma unroll
            for (int r = 0; r < 4; ++r)
                C[(size_t)(row0 + r) * N + col] = acc[i][j][r] + bz[j];
        }
    }
}

// ---------------------------------------------------------------------------
extern "C" void kernel_launch(void* const* d_in, const int* in_sizes, int n_in,
                              void* d_out, int out_size, void* d_ws, size_t ws_size,
                              hipStream_t stream) {
    const float* x    = (const float*)d_in[0];
    const float* w    = (const float*)d_in[1];
    const float* bias = (const float*)d_in[2];
    float* out = (float*)d_out;

    const int N = in_sizes[2];            // bias length = out features
    const int K = in_sizes[1] / N;        // weight is [N, K]
    const int M = in_sizes[0] / K;        // x is [M, K] flattened

    uint16_t* dqx = (uint16_t*)d_ws;              // [M,K] bf16
    uint16_t* dqw = dqx + (size_t)M * K;          // [N,K] bf16

    const int nx4 = (M * K) / 4;
    const int nw4 = (N * K) / 4;
    quant_dq_kernel<<<(nx4 + 255) / 256, 256, 0, stream>>>(x, dqx, nx4);
    quant_dq_kernel<<<(nw4 + 255) / 256, 256, 0, stream>>>(w, dqw, nw4);

    dim3 grid(N / BN, M / BM);
    gemm_bt_bias<<<grid, 256, 0, stream>>>(dqx, dqw, bias, out, M, N, K);
}

// Round 3
// 321.628 us; speedup vs baseline: 1.1006x; 1.1006x over previous
//
#include <hip/hip_runtime.h>
#include <hip/hip_bf16.h>
#include <stdint.h>

typedef __attribute__((ext_vector_type(8))) __bf16 bf16x8;
typedef __attribute__((ext_vector_type(4))) float floatx4;

// ---------------------------------------------------------------------------
// f32 -> bf16 round-to-nearest-even (values produced here are exactly
// representable in bf16: e4m3 grid x power-of-two scale -> <=5 significant bits)
__device__ __forceinline__ uint16_t f32_to_bf16_rn(float f) {
    uint32_t u = __float_as_uint(f);
    uint32_t r = u + 0x7FFFu + ((u >> 16) & 1u);
    return (uint16_t)(r >> 16);
}

// ---------------------------------------------------------------------------
// MX quant (block=32 along K, e8m0 shared scale, e4m3 element grid, rint)
// then immediate dequant, stored as bf16 (exact). One lane = 4 consecutive
// floats; 8 lanes = one MX block. [PASSED round 1, absmax 0.031 — unchanged]
__global__ __launch_bounds__(256) void quant_dq_kernel(
    const float* __restrict__ in, uint16_t* __restrict__ out, int n4)
{
    int t = blockIdx.x * blockDim.x + threadIdx.x;
    if (t >= n4) return;
    float4 v = ((const float4*)in)[t];

    float am = fmaxf(fmaxf(fabsf(v.x), fabsf(v.y)), fmaxf(fabsf(v.z), fabsf(v.w)));
    am = fmaxf(am, __shfl_xor(am, 1));
    am = fmaxf(am, __shfl_xor(am, 2));
    am = fmaxf(am, __shfl_xor(am, 4));

    float scale, iscale;
    if (am > 0.0f) {
        // floor(log2(am)) == exponent field - 127 (subnormal -> -127, matches ref clip)
        int se = (int)((__float_as_uint(am) >> 23) & 0xFF) - 135;  // -127-8
        se = se < -127 ? -127 : se;
        scale  = __uint_as_float((uint32_t)(se + 127) << 23);
        iscale = __uint_as_float((uint32_t)(127 - se) << 23);
    } else {
        scale = 1.0f; iscale = 1.0f;
    }

    float r[4] = {v.x, v.y, v.z, v.w};
    uint16_t o[4];
#pragma unroll
    for (int i = 0; i < 4; ++i) {
        float sv = r[i] * iscale;              // exact (power-of-two)
        float a  = fabsf(sv);
        int e = (int)((__float_as_uint(a) >> 23) & 0xFF) - 127;
        e = e < -6 ? -6 : (e > 8 ? 8 : e);
        float step  = __uint_as_float((uint32_t)(e - 3 + 127) << 23);
        float rstep = __uint_as_float((uint32_t)(3 - e + 127) << 23);
        float q = rintf(a * rstep) * step;     // exact grid snap, RNE like jnp.round
        q = fminf(q, 448.0f);
        float dq = copysignf(q, sv) * scale;   // exact in bf16
        o[i] = f32_to_bf16_rn(dq);
    }
    ((ushort4*)out)[t] = make_ushort4(o[0], o[1], o[2], o[3]);
}

// ---------------------------------------------------------------------------
// bf16 GEMM, C[M,N] = A[M,K] * B[N,K]^T + bias[N]
// 128x128 block tile, BK=64, 256 threads (2x2 waves, each wave 4x4 tiles of
// 16x16x32 MFMA), global_load_lds width=16 staging.
// NEW vs round 1: XOR chunk swizzle — LDS slot s of row r holds global 16B
// chunk s^(r&7). Kills the 5.0e7 bank-conflict cycles (row stride 128 B = 32
// banks meant 16 lanes/quarter-wave hit the same 4 banks on each ds_read_b128;
// swizzled slots spread all 32 banks at 2-way aliasing, which is free).
#define BM 128
#define BN 128
#define BK 64

__global__ __launch_bounds__(256) void gemm_bt_bias(
    const uint16_t* __restrict__ A, const uint16_t* __restrict__ B,
    const float* __restrict__ bias, float* __restrict__ C,
    int M, int N, int K)
{
    __shared__ uint16_t sA[BM * BK];   // [row][k], 128 B per row
    __shared__ uint16_t sB[BN * BK];

    const int tid  = threadIdx.x;
    const int wave = tid >> 6;
    const int lane = tid & 63;

    const int bm = blockIdx.y * BM;
    const int bn = blockIdx.x * BN;

    // staging: per call 8 rows x 128 B; lane l -> LDS row l>>3, slot l&7
    // (HW scatter = uniform base + lane*16). Global source chunk permuted so
    // LDS[row][slot s] = global chunk s ^ (row&7). Same 128B line -> still
    // fully coalesced.
    const int srow8  = lane >> 3;
    const int schunk = (lane & 7) ^ srow8;     // row&7 == srow8 for all calls
    const int wrow   = wave * 32;

    const uint16_t* Ag = A + (size_t)(bm + wrow + srow8) * K + schunk * 8;
    const uint16_t* Bg = B + (size_t)(bn + wrow + srow8) * K + schunk * 8;

    const int wm = (wave & 1) * 64;
    const int wn = (wave >> 1) * 64;
    const int fr = lane & 15;   // m (A) / n (B) index within 16-tile
    const int fq = lane >> 4;   // quad -> k offset fq*8
    const int sw = fr & 7;      // read-side swizzle key (row&7 == fr&7)

    floatx4 zero = {0.0f, 0.0f, 0.0f, 0.0f};
    floatx4 acc[4][4];
#pragma unroll
    for (int i = 0; i < 4; ++i)
#pragma unroll
        for (int j = 0; j < 4; ++j) acc[i][j] = zero;

    for (int k0 = 0; k0 < K; k0 += BK) {
        __syncthreads();   // protect LDS from overwrite while prior tile in use
#pragma unroll
        for (int c = 0; c < 4; ++c) {
            __builtin_amdgcn_global_load_lds(
                (const __attribute__((address_space(1))) void*)(Ag + (size_t)c * 8 * K + k0),
                (__attribute__((address_space(3))) void*)(sA + (wrow + c * 8) * BK),
                16, 0, 0);
        }
#pragma unroll
        for (int c = 0; c < 4; ++c) {
            __builtin_amdgcn_global_load_lds(
                (const __attribute__((address_space(1))) void*)(Bg + (size_t)c * 8 * K + k0),
                (__attribute__((address_space(3))) void*)(sB + (wrow + c * 8) * BK),
                16, 0, 0);
        }
        __syncthreads();   // drains vmcnt before LDS reads

#pragma unroll
        for (int kk = 0; kk < BK; kk += 32) {
            const int cb = (kk >> 3) + fq;      // global chunk wanted
            const int sl = cb ^ sw;             // swizzled LDS slot
            bf16x8 af[4], bf[4];
#pragma unroll
            for (int u = 0; u < 4; ++u)
                af[u] = *(const bf16x8*)(sA + (wm + u * 16 + fr) * BK + sl * 8);
#pragma unroll
            for (int u = 0; u < 4; ++u)
                bf[u] = *(const bf16x8*)(sB + (wn + u * 16 + fr) * BK + sl * 8);
#pragma unroll
            for (int i = 0; i < 4; ++i)
#pragma unroll
                for (int j = 0; j < 4; ++j)
                    acc[i][j] = __builtin_amdgcn_mfma_f32_16x16x32_bf16(
                        af[i], bf[j], acc[i][j], 0, 0, 0);
        }
    }

    // epilogue: C/D layout col = lane&15, row = (lane>>4)*4 + reg
    float bz[4];
#pragma unroll
    for (int j = 0; j < 4; ++j) bz[j] = bias[bn + wn + j * 16 + fr];

#pragma unroll
    for (int i = 0; i < 4; ++i) {
        int row0 = bm + wm + i * 16 + fq * 4;
#pragma unroll
        for (int j = 0; j < 4; ++j) {
            int col = bn + wn + j * 16 + fr;
#pragma unroll
            for (int r = 0; r < 4; ++r)
                C[(size_t)(row0 + r) * N + col] = acc[i][j][r] + bz[j];
        }
    }
}

// ---------------------------------------------------------------------------
extern "C" void kernel_launch(void* const* d_in, const int* in_sizes, int n_in,
                              void* d_out, int out_size, void* d_ws, size_t ws_size,
                              hipStream_t stream) {
    const float* x    = (const float*)d_in[0];
    const float* w    = (const float*)d_in[1];
    const float* bias = (const float*)d_in[2];
    float* out = (float*)d_out;

    const int N = in_sizes[2];            // bias length = out features
    const int K = in_sizes[1] / N;        // weight is [N, K]
    const int M = in_sizes[0] / K;        // x is [M, K] flattened

    uint16_t* dqx = (uint16_t*)d_ws;              // [M,K] bf16
    uint16_t* dqw = dqx + (size_t)M * K;          // [N,K] bf16

    const int nx4 = (M * K) / 4;
    const int nw4 = (N * K) / 4;
    quant_dq_kernel<<<(nx4 + 255) / 256, 256, 0, stream>>>(x, dqx, nx4);
    quant_dq_kernel<<<(nw4 + 255) / 256, 256, 0, stream>>>(w, dqw, nw4);

    dim3 grid(N / BN, M / BM);
    gemm_bt_bias<<<grid, 256, 0, stream>>>(dqx, dqw, bias, out, M, N, K);
}

// Round 5
// 317.806 us; speedup vs baseline: 1.1138x; 1.0120x over previous
//
#include <hip/hip_runtime.h>
#include <hip/hip_bf16.h>
#include <stdint.h>

typedef __attribute__((ext_vector_type(8)))  __bf16 bf16x8;
typedef __attribute__((ext_vector_type(16))) float  floatx16;

// ---------------------------------------------------------------------------
// f32 -> bf16 RNE (values here are exactly representable: e4m3 grid x pow2)
__device__ __forceinline__ uint16_t f32_to_bf16_rn(float f) {
    uint32_t u = __float_as_uint(f);
    uint32_t r = u + 0x7FFFu + ((u >> 16) & 1u);
    return (uint16_t)(r >> 16);
}

// ---------------------------------------------------------------------------
// MX quant (block=32 along K, e8m0 scale, e4m3 grid, rint) + dequant to bf16,
// for BOTH tensors in one launch (boundary nx4 is block-aligned -> uniform
// branch). One lane = 4 consecutive floats; 8 lanes = one MX block.
__global__ __launch_bounds__(256) void quant_dq2_kernel(
    const float* __restrict__ x, const float* __restrict__ w,
    uint16_t* __restrict__ dqx, uint16_t* __restrict__ dqw,
    int nx4, int ntot4)
{
    int t = blockIdx.x * blockDim.x + threadIdx.x;
    if (t >= ntot4) return;
    const float* src; uint16_t* dst; int idx;
    if (t < nx4) { src = x; dst = dqx; idx = t; }
    else         { src = w; dst = dqw; idx = t - nx4; }

    float4 v = ((const float4*)src)[idx];

    float am = fmaxf(fmaxf(fabsf(v.x), fabsf(v.y)), fmaxf(fabsf(v.z), fabsf(v.w)));
    am = fmaxf(am, __shfl_xor(am, 1));
    am = fmaxf(am, __shfl_xor(am, 2));
    am = fmaxf(am, __shfl_xor(am, 4));

    float scale, iscale;
    if (am > 0.0f) {
        // floor(log2(am)) == exponent field - 127 (subnormal -> -127 = ref clip)
        int se = (int)((__float_as_uint(am) >> 23) & 0xFF) - 135;  // -127-8
        se = se < -127 ? -127 : se;
        scale  = __uint_as_float((uint32_t)(se + 127) << 23);
        iscale = __uint_as_float((uint32_t)(127 - se) << 23);
    } else {
        scale = 1.0f; iscale = 1.0f;
    }

    float r[4] = {v.x, v.y, v.z, v.w};
    uint16_t o[4];
#pragma unroll
    for (int i = 0; i < 4; ++i) {
        float sv = r[i] * iscale;              // exact (power-of-two)
        float a  = fabsf(sv);
        int e = (int)((__float_as_uint(a) >> 23) & 0xFF) - 127;
        e = e < -6 ? -6 : (e > 8 ? 8 : e);
        float step  = __uint_as_float((uint32_t)(e - 3 + 127) << 23);
        float rstep = __uint_as_float((uint32_t)(3 - e + 127) << 23);
        float q = rintf(a * rstep) * step;     // exact grid snap, RNE like jnp.round
        q = fminf(q, 448.0f);
        float dq = copysignf(q, sv) * scale;   // exact in bf16
        o[i] = f32_to_bf16_rn(dq);
    }
    ((ushort4*)dst)[idx] = make_ushort4(o[0], o[1], o[2], o[3]);
}

// ---------------------------------------------------------------------------
// bf16 GEMM, C[M,N] = A[M,K]*B[N,K]^T + bias[N].
// 128x128 block tile, BK=64, 256 threads (2x2 waves, each wave 2x2 tiles of
// 32x32x16 MFMA = 64x64). Staging + XOR chunk swizzle identical to round 3
// (verified: 0 staging-side conflicts). 32x32 MFMA doubles FLOP/instruction
// (4096 vs 3378 FLOP/cyc ceiling) at the cost of 4-way LDS read aliasing
// (32 rows over 8 swizzle slots — irreducible with 16B granules; LDS traffic
// ~6 TB/s vs 69 ceiling, so throughput impact is small).
#define BM 128
#define BN 128
#define BK 64

__global__ __launch_bounds__(256) void gemm_bt_bias(
    const uint16_t* __restrict__ A, const uint16_t* __restrict__ B,
    const float* __restrict__ bias, float* __restrict__ C,
    int M, int N, int K)
{
    __shared__ uint16_t sA[BM * BK];   // [row][k], 128 B per row
    __shared__ uint16_t sB[BN * BK];

    const int tid  = threadIdx.x;
    const int wave = tid >> 6;
    const int lane = tid & 63;

    const int bm = blockIdx.y * BM;
    const int bn = blockIdx.x * BN;

    // staging (unchanged from round 3): per call 8 rows x 128 B; lane l ->
    // LDS row l>>3, slot l&7; source chunk permuted so LDS[r][slot s] holds
    // global chunk s^(r&7). Same 128B line -> fully coalesced.
    const int srow8  = lane >> 3;
    const int schunk = (lane & 7) ^ srow8;
    const int wrow   = wave * 32;

    const uint16_t* Ag = A + (size_t)(bm + wrow + srow8) * K + schunk * 8;
    const uint16_t* Bg = B + (size_t)(bn + wrow + srow8) * K + schunk * 8;

    const int wm  = (wave & 1) * 64;
    const int wn  = (wave >> 1) * 64;
    const int m32 = lane & 31;      // row/col within a 32-tile
    const int h   = lane >> 5;      // k-half: elements [h*8, h*8+8) of K=16
    const int swz = m32 & 7;        // read-side swizzle key (row&7)

    floatx16 acc[2][2];
#pragma unroll
    for (int i = 0; i < 2; ++i)
#pragma unroll
        for (int j = 0; j < 2; ++j)
#pragma unroll
            for (int r = 0; r < 16; ++r) acc[i][j][r] = 0.0f;

    for (int k0 = 0; k0 < K; k0 += BK) {
        __syncthreads();   // protect LDS while prior tile in use
#pragma unroll
        for (int c = 0; c < 4; ++c) {
            __builtin_amdgcn_global_load_lds(
                (const __attribute__((address_space(1))) void*)(Ag + (size_t)c * 8 * K + k0),
                (__attribute__((address_space(3))) void*)(sA + (wrow + c * 8) * BK),
                16, 0, 0);
        }
#pragma unroll
        for (int c = 0; c < 4; ++c) {
            __builtin_amdgcn_global_load_lds(
                (const __attribute__((address_space(1))) void*)(Bg + (size_t)c * 8 * K + k0),
                (__attribute__((address_space(3))) void*)(sB + (wrow + c * 8) * BK),
                16, 0, 0);
        }
        __syncthreads();   // drains vmcnt before LDS reads

#pragma unroll
        for (int kk = 0; kk < 4; ++kk) {        // 4 K=16 steps per BK=64
            const int chunk = kk * 2 + h;       // wanted global 16B chunk
            const int slot  = chunk ^ swz;      // swizzled LDS slot
            bf16x8 a0 = *(const bf16x8*)(sA + (wm      + m32) * BK + slot * 8);
            bf16x8 a1 = *(const bf16x8*)(sA + (wm + 32 + m32) * BK + slot * 8);
            bf16x8 b0 = *(const bf16x8*)(sB + (wn      + m32) * BK + slot * 8);
            bf16x8 b1 = *(const bf16x8*)(sB + (wn + 32 + m32) * BK + slot * 8);
            acc[0][0] = __builtin_amdgcn_mfma_f32_32x32x16_bf16(a0, b0, acc[0][0], 0, 0, 0);
            acc[0][1] = __builtin_amdgcn_mfma_f32_32x32x16_bf16(a0, b1, acc[0][1], 0, 0, 0);
            acc[1][0] = __builtin_amdgcn_mfma_f32_32x32x16_bf16(a1, b0, acc[1][0], 0, 0, 0);
            acc[1][1] = __builtin_amdgcn_mfma_f32_32x32x16_bf16(a1, b1, acc[1][1], 0, 0, 0);
        }
    }

    // epilogue: 32x32 C/D layout col = lane&31, row = (reg&3)+8*(reg>>2)+4*h
    // [measured: learn_hip m74/m101]
#pragma unroll
    for (int j = 0; j < 2; ++j) {
        const int col = bn + wn + j * 32 + m32;
        const float bz = bias[col];
#pragma unroll
        for (int i = 0; i < 2; ++i) {
            const int rbase = bm + wm + i * 32 + 4 * h;
#pragma unroll
            for (int r = 0; r < 16; ++r) {
                const int row = rbase + (r & 3) + 8 * (r >> 2);
                C[(size_t)row * N + col] = acc[i][j][r] + bz;
            }
        }
    }
}

// ---------------------------------------------------------------------------
extern "C" void kernel_launch(void* const* d_in, const int* in_sizes, int n_in,
                              void* d_out, int out_size, void* d_ws, size_t ws_size,
                              hipStream_t stream) {
    const float* x    = (const float*)d_in[0];
    const float* w    = (const float*)d_in[1];
    const float* bias = (const float*)d_in[2];
    float* out = (float*)d_out;

    const int N = in_sizes[2];            // bias length = out features
    const int K = in_sizes[1] / N;        // weight is [N, K]
    const int M = in_sizes[0] / K;        // x is [M, K] flattened

    uint16_t* dqx = (uint16_t*)d_ws;              // [M,K] bf16
    uint16_t* dqw = dqx + (size_t)M * K;          // [N,K] bf16

    const int nx4   = (M * K) / 4;
    const int ntot4 = nx4 + (N * K) / 4;
    quant_dq2_kernel<<<(ntot4 + 255) / 256, 256, 0, stream>>>(x, w, dqx, dqw, nx4, ntot4);

    dim3 grid(N / BN, M / BM);
    gemm_bt_bias<<<grid, 256, 0, stream>>>(dqx, dqw, bias, out, M, N, K);
}